// Round 4
// baseline (364.837 us; speedup 1.0000x reference)
//
#include <hip/hip_runtime.h>
#include <hip/hip_bf16.h>
#include <math.h>

typedef unsigned short u16;
typedef __attribute__((ext_vector_type(4))) unsigned short u16x4;
typedef __attribute__((ext_vector_type(8))) unsigned short u16x8;
typedef __attribute__((ext_vector_type(8))) short s16x8;
typedef __attribute__((ext_vector_type(4))) float f32x4;

#define B_  4
#define S_  2048
#define D_  2048
#define DI_ 1024
#define MROWS (B_ * S_)          // 8192
#define KDIM  D_                 // 2048
#define NDIM  D_                 // 2048
#define STRIP 16                 // rows per conv strip (divides S_)

__device__ __forceinline__ float b2f(u16 u) {
    union { unsigned i; float f; } v; v.i = ((unsigned)u) << 16; return v.f;
}
__device__ __forceinline__ u16 f2b(float f) {
    unsigned u = __float_as_uint(f);
    unsigned r = (u + 0x7FFFu + ((u >> 16) & 1u)) >> 16;
    return (u16)r;
}
__device__ __forceinline__ float gelu_exact(float x) {
    return 0.5f * x * (1.0f + erff(x * 0.70710678118654752f));
}

#define GLOAD_LDS16(gp, lp)                                                    \
    __builtin_amdgcn_global_load_lds(                                          \
        (const __attribute__((address_space(1))) void*)(gp),                   \
        (__attribute__((address_space(3))) void*)(lp), 16, 0, 0)

// ---------------------------------------------------------------------------
// Transpose n x n, fp32 in -> bf16 out. blockIdx.z picks src/dst when dual.
// ---------------------------------------------------------------------------
__global__ void transpose_k(const float* __restrict__ in0, u16* __restrict__ out0,
                            const float* __restrict__ in1, u16* __restrict__ out1,
                            int n) {
    __shared__ float tile[32][33];
    const float* in = (blockIdx.z == 0) ? in0 : in1;
    u16* out = (blockIdx.z == 0) ? out0 : out1;
    int bx = blockIdx.x * 32, by = blockIdx.y * 32;
    int tx = threadIdx.x, ty = threadIdx.y;
    for (int i = 0; i < 32; i += 8)
        tile[ty + i][tx] = in[(size_t)(by + ty + i) * n + bx + tx];
    __syncthreads();
    for (int i = 0; i < 32; i += 8)
        out[(size_t)(bx + ty + i) * n + by + tx] = f2b(tile[tx][ty + i]);
}

// ---------------------------------------------------------------------------
// Short conv, strip-mined (fp32 in, bf16 out). Also zeroes wacc and t_g.
// ---------------------------------------------------------------------------
__global__ void shortconv_k(const float* __restrict__ x, const float* __restrict__ sw,
                            const float* __restrict__ sb, u16* __restrict__ xs,
                            float* __restrict__ wacc, float* __restrict__ t_g) {
    const int bid = blockIdx.y * 2 + blockIdx.x;
    {
        int z = bid * 256 + threadIdx.x;
        if (z < 12) wacc[z] = 0.0f;
        if (z < MROWS * 6) t_g[z] = 0.0f;
    }
    const int c = blockIdx.x * 1024 + threadIdx.x * 4;
    const int r0 = blockIdx.y * STRIP;
    const int t0 = r0 & (S_ - 1);

    float tap[12];
    #pragma unroll
    for (int q = 0; q < 3; ++q)
        ((f32x4*)tap)[q] = *(const f32x4*)(sw + (size_t)c * 3 + q * 4);
    f32x4 sbv = *(const f32x4*)(sb + c);

    const float* base = x + (size_t)r0 * D_ + c;
    f32x4 m2, m1;
    if (t0 == 0) { m2 = (f32x4)(0.0f); m1 = (f32x4)(0.0f); }
    else { m2 = *(const f32x4*)(base - 2 * D_); m1 = *(const f32x4*)(base - D_); }

    u16* op = xs + (size_t)r0 * D_ + c;
    #pragma unroll
    for (int rr = 0; rr < STRIP; ++rr) {
        f32x4 cur = *(const f32x4*)(base + (size_t)rr * D_);
        u16x4 outv;
        #pragma unroll
        for (int e = 0; e < 4; ++e) {
            float v = cur[e] + sbv[e]
                    + tap[e * 3 + 0] * m2[e]
                    + tap[e * 3 + 1] * m1[e]
                    + tap[e * 3 + 2] * cur[e];
            outv[e] = f2b(v);
        }
        *(u16x4*)(op + (size_t)rr * D_) = outv;
        m2 = m1; m1 = cur;
    }
}

// ===========================================================================
// Shared GEMM pieces: 256x256 tile, BK=32 regions x4 (128 KiB LDS ring),
// 8 waves (2Mx4N), per-wave 128x64 output, acc[8][4] f32x4.
// Staging: linear LDS dest + pre-swizzled global source; fragment ds_reads
// use matching XOR chunk swizzle (measured conflict-free).
// ===========================================================================
#define STG_A(REG, KOFF) do { const u16* _g = gA + (KOFF);                     \
    GLOAD_LDS16(_g, &As[REG][ldsW0]);                                          \
    GLOAD_LDS16(_g + (size_t)128 * KDIM, &As[REG][ldsW1]); } while (0)
#define STG_B(REG, KOFF) do { const u16* _g = gB + (KOFF);                     \
    GLOAD_LDS16(_g, &Bs[REG][ldsW0]);                                          \
    GLOAD_LDS16(_g + (size_t)128 * KDIM, &Bs[REG][ldsW1]); } while (0)
#define LD_B4(REG) do {                                                        \
    bf[0] = *(const s16x8*)&Bs[REG][boffR[0]];                                 \
    bf[1] = *(const s16x8*)&Bs[REG][boffR[1]];                                 \
    bf[2] = *(const s16x8*)&Bs[REG][boffR[2]];                                 \
    bf[3] = *(const s16x8*)&Bs[REG][boffR[3]]; } while (0)
#define LD_A4(REG, I0) do {                                                    \
    af[0] = *(const s16x8*)&As[REG][aoffR[(I0) + 0]];                          \
    af[1] = *(const s16x8*)&As[REG][aoffR[(I0) + 1]];                          \
    af[2] = *(const s16x8*)&As[REG][aoffR[(I0) + 2]];                          \
    af[3] = *(const s16x8*)&As[REG][aoffR[(I0) + 3]]; } while (0)
#define LD_A8(REG) do {                                                        \
    af[0] = *(const s16x8*)&As[REG][aoffR[0]];                                 \
    af[1] = *(const s16x8*)&As[REG][aoffR[1]];                                 \
    af[2] = *(const s16x8*)&As[REG][aoffR[2]];                                 \
    af[3] = *(const s16x8*)&As[REG][aoffR[3]];                                 \
    af[4] = *(const s16x8*)&As[REG][aoffR[4]];                                 \
    af[5] = *(const s16x8*)&As[REG][aoffR[5]];                                 \
    af[6] = *(const s16x8*)&As[REG][aoffR[6]];                                 \
    af[7] = *(const s16x8*)&As[REG][aoffR[7]]; } while (0)
#define MFMA16(I0) do { __builtin_amdgcn_s_setprio(1);                         \
    _Pragma("unroll")                                                          \
    for (int i_ = 0; i_ < 4; ++i_) {                                           \
        _Pragma("unroll")                                                      \
        for (int j_ = 0; j_ < 4; ++j_)                                         \
            acc[(I0) + i_][j_] = __builtin_amdgcn_mfma_f32_16x16x32_bf16(      \
                af[i_], bf[j_], acc[(I0) + i_][j_], 0, 0, 0);                  \
    }                                                                          \
    __builtin_amdgcn_s_setprio(0); } while (0)
#define MFMA32() do { __builtin_amdgcn_s_setprio(1);                           \
    _Pragma("unroll")                                                          \
    for (int i_ = 0; i_ < 8; ++i_) {                                           \
        _Pragma("unroll")                                                      \
        for (int j_ = 0; j_ < 4; ++j_)                                         \
            acc[i_][j_] = __builtin_amdgcn_mfma_f32_16x16x32_bf16(             \
                af[i_], bf[j_], acc[i_][j_], 0, 0, 0);                         \
    }                                                                          \
    __builtin_amdgcn_s_setprio(0); } while (0)
#define BARR() __builtin_amdgcn_s_barrier()
#define LGKM0() asm volatile("s_waitcnt lgkmcnt(0)" ::: "memory")
#define VM8() asm volatile("s_waitcnt vmcnt(8)" ::: "memory")
#define VM4() asm volatile("s_waitcnt vmcnt(4)" ::: "memory")
#define VM0() asm volatile("s_waitcnt vmcnt(0)" ::: "memory")
#define VMNOP()

#define GEMM_PRE(APTR, BPTR)                                                   \
    __shared__ u16 As[4][8192];                                                \
    __shared__ u16 Bs[4][8192];                                                \
    const int tid  = threadIdx.x;                                              \
    const int wid  = tid >> 6;                                                 \
    const int lane = tid & 63;                                                 \
    const int wr   = wid >> 2;                                                 \
    const int wc   = wid & 3;                                                  \
    const int row0 = blockIdx.y << 8;                                          \
    const int col0 = blockIdx.x << 8;                                          \
    const int rowS    = tid >> 2;                                              \
    const int colOffS = (((tid & 3) ^ ((rowS >> 1) & 3)) << 3);                \
    const u16* gA = (APTR) + (size_t)(row0 + rowS) * KDIM + colOffS;           \
    const u16* gB = (BPTR) + (size_t)(col0 + rowS) * KDIM + colOffS;           \
    const int ldsW0 = wid * 512;                                               \
    const int ldsW1 = 4096 + wid * 512;                                        \
    int aoffR[8], boffR[4];                                                    \
    _Pragma("unroll")                                                          \
    for (int i = 0; i < 8; ++i) {                                              \
        int row  = (wr << 7) + (i << 4) + (lane & 15);                         \
        int slot = (lane >> 4) ^ ((row >> 1) & 3);                             \
        aoffR[i] = row * 32 + slot * 8;                                        \
    }                                                                          \
    _Pragma("unroll")                                                          \
    for (int j = 0; j < 4; ++j) {                                              \
        int row  = (wc << 6) + (j << 4) + (lane & 15);                         \
        int slot = (lane >> 4) ^ ((row >> 1) & 3);                             \
        boffR[j] = row * 32 + slot * 8;                                        \
    }                                                                          \
    f32x4 acc[8][4];                                                           \
    _Pragma("unroll")                                                          \
    for (int i = 0; i < 8; ++i)                                                \
        _Pragma("unroll")                                                      \
        for (int j = 0; j < 4; ++j) acc[i][j] = (f32x4)(0.0f);                 \
    s16x8 af[8], bf[4];

// ---------------------------------------------------------------------------
// CORE4 (arm A): merged 4-phase schedule — 12 ds_read + full-region stage
// per phase, 32 MFMA per phase, HALF the sync points (8/iter vs 16).
// Phase p: read region p, stage region (p+3)&3 @ kb+96+32p. VM8 every
// phase end => stage forced landed 2 phases after issue; reads use data
// staged 3 phases earlier (RAW ok); WAR: barrier at prior phase end.
// Final iter: stage only at P0; VM8@P0, VM4@P1, VM0@P2.
// ---------------------------------------------------------------------------
#define PH4(RD, STREG, KOFF, DOSTG, VMW) do {                                  \
    LD_B4(RD); LD_A8(RD);                                                      \
    if (DOSTG) { STG_A(STREG, KOFF); STG_B(STREG, KOFF); }                     \
    BARR(); LGKM0();                                                           \
    __builtin_amdgcn_sched_barrier(0);                                         \
    MFMA32();                                                                  \
    VMW; BARR(); } while (0)

#define GEMM_CORE4(APTR, BPTR)                                                 \
    GEMM_PRE(APTR, BPTR)                                                       \
    STG_A(0, 0);  STG_B(0, 0);                                                 \
    STG_A(1, 32); STG_B(1, 32);                                                \
    STG_A(2, 64); STG_B(2, 64);                                                \
    VM8();                                                                     \
    BARR();                                                                    \
    _Pragma("unroll 1")                                                        \
    for (int t = 0; t < 15; ++t) {                                             \
        const int kb = t * 128;                                                \
        PH4(0, 3, kb + 96,  1, VM8());                                         \
        PH4(1, 0, kb + 128, 1, VM8());                                         \
        PH4(2, 1, kb + 160, 1, VM8());                                         \
        PH4(3, 2, kb + 192, 1, VM8());                                         \
    }                                                                          \
    {                                                                          \
        const int kb = 15 * 128;                                               \
        PH4(0, 3, kb + 96, 1, VM8());                                          \
        PH4(1, 0, 0,       0, VM4());                                          \
        PH4(2, 0, 0,       0, VM0());                                          \
        PH4(3, 0, 0,       0, VMNOP());                                        \
    }

// ---------------------------------------------------------------------------
// CORE8NS (arm B): round-3 8-phase schedule with sched_barrier(0) REMOVED
// from the sync (lgkmcnt(0) asm retained — still forces ds_read completion
// before the phase-end barrier, so staging WAR/RAW safety is unchanged).
// ---------------------------------------------------------------------------
#define SYNC_NS() do { BARR(); LGKM0(); } while (0)

#define GEMM_CORE8NS(APTR, BPTR)                                               \
    GEMM_PRE(APTR, BPTR)                                                       \
    STG_A(0, 0);  STG_B(0, 0);                                                 \
    STG_A(1, 32); STG_B(1, 32);                                                \
    STG_A(2, 64); STG_B(2, 64);                                                \
    VM8();                                                                     \
    BARR();                                                                    \
    _Pragma("unroll 1")                                                        \
    for (int t = 0; t < 15; ++t) {                                             \
        const int kb = t * 128;                                                \
        LD_B4(0); LD_A4(0,0); STG_A(3, kb + 96);  SYNC_NS(); MFMA16(0); BARR();        \
        LD_A4(0,4);           STG_B(3, kb + 96);  SYNC_NS(); MFMA16(4); VM8(); BARR(); \
        LD_B4(1); LD_A4(1,0); STG_A(0, kb + 128); SYNC_NS(); MFMA16(0); BARR();        \
        LD_A4(1,4);           STG_B(0, kb + 128); SYNC_NS(); MFMA16(4); VM8(); BARR(); \
        LD_B4(2); LD_A4(2,0); STG_A(1, kb + 160); SYNC_NS(); MFMA16(0); BARR();        \
        LD_A4(2,4);           STG_B(1, kb + 160); SYNC_NS(); MFMA16(4); VM8(); BARR(); \
        LD_B4(3); LD_A4(3,0); STG_A(2, kb + 192); SYNC_NS(); MFMA16(0); BARR();        \
        LD_A4(3,4);           STG_B(2, kb + 192); SYNC_NS(); MFMA16(4); VM8(); BARR(); \
    }                                                                          \
    {                                                                          \
        const int kb = 15 * 128;                                               \
        LD_B4(0); LD_A4(0,0); STG_A(3, kb + 96);  SYNC_NS(); MFMA16(0); BARR();        \
        LD_A4(0,4);           STG_B(3, kb + 96);  SYNC_NS(); MFMA16(4); VM8(); BARR(); \
        LD_B4(1); LD_A4(1,0);                     SYNC_NS(); MFMA16(0); BARR();        \
        LD_A4(1,4);                               SYNC_NS(); MFMA16(4); VM4(); BARR(); \
        LD_B4(2); LD_A4(2,0);                     SYNC_NS(); MFMA16(0); BARR();        \
        LD_A4(2,4);                               SYNC_NS(); MFMA16(4); VM0(); BARR(); \
        LD_B4(3); LD_A4(3,0);                     SYNC_NS(); MFMA16(0); BARR();        \
        LD_A4(3,4);                               SYNC_NS(); MFMA16(4); BARR();        \
    }

// ---------------------------------------------------------------------------
// GEMM1 (FILT), CORE4 arm: epilogue folds gelu(acc+bias)*fw into t_g.
// ---------------------------------------------------------------------------
__global__ __launch_bounds__(512, 2)
void gemm_f8(const u16* __restrict__ A, const u16* __restrict__ BT,
             const float* __restrict__ bias,
             const float* __restrict__ fw, float* __restrict__ t_g) {
    GEMM_CORE4(A, BT)

    __shared__ float t_lds[768];
    __syncthreads();
    for (int z = tid; z < 768; z += 512) t_lds[z] = 0.0f;
    __syncthreads();

    const int colt0 = (wc << 6) + (lane & 15);
    float fwv[4][3], bsv[4];
    const int ibase = (col0 & (DI_ - 1)) + colt0;
    #pragma unroll
    for (int j = 0; j < 4; ++j) {
        int ifilt = ibase + j * 16;
        fwv[j][0] = fw[ifilt * 3 + 0];
        fwv[j][1] = fw[ifilt * 3 + 1];
        fwv[j][2] = fw[ifilt * 3 + 2];
        bsv[j] = bias[col0 + colt0 + j * 16];
    }
    #pragma unroll
    for (int i = 0; i < 8; ++i) {
        #pragma unroll
        for (int r = 0; r < 4; ++r) {
            float s0 = 0.f, s1 = 0.f, s2 = 0.f;
            #pragma unroll
            for (int j = 0; j < 4; ++j) {
                float hv = gelu_exact(acc[i][j][r] + bsv[j]);
                s0 += hv * fwv[j][0];
                s1 += hv * fwv[j][1];
                s2 += hv * fwv[j][2];
            }
            #pragma unroll
            for (int m = 1; m < 16; m <<= 1) {
                s0 += __shfl_xor(s0, m, 16);
                s1 += __shfl_xor(s1, m, 16);
                s2 += __shfl_xor(s2, m, 16);
            }
            if ((lane & 15) == 0) {
                int trow = (wr << 7) + ((lane >> 4) << 2) + (i << 4) + r;
                atomicAdd(&t_lds[trow * 3 + 0], s0);
                atomicAdd(&t_lds[trow * 3 + 1], s1);
                atomicAdd(&t_lds[trow * 3 + 2], s2);
            }
        }
    }
    __syncthreads();
    const int f3 = (col0 >= DI_) ? 3 : 0;
    for (int z = tid; z < 768; z += 512) {
        int rr = z / 3, k = z - rr * 3;
        atomicAdd(&t_g[(size_t)(row0 + rr) * 6 + f3 + k], t_lds[z]);
    }
}

// ---------------------------------------------------------------------------
// GEMM2 (plain), CORE8NS arm: C fp32 = acc + bias.
// ---------------------------------------------------------------------------
__global__ __launch_bounds__(512, 2)
void gemm8_k(const u16* __restrict__ A, const u16* __restrict__ BT,
             const float* __restrict__ bias, float* __restrict__ C) {
    GEMM_CORE8NS(A, BT)

    const int colt0 = (wc << 6) + (lane & 15);
    const int crow0 = row0 + (wr << 7) + ((lane >> 4) << 2);
    #pragma unroll
    for (int j = 0; j < 4; ++j) {
        int col = col0 + colt0 + j * 16;
        float bs = bias[col];
        #pragma unroll
        for (int i = 0; i < 8; ++i) {
            int rbase = crow0 + i * 16;
            #pragma unroll
            for (int r = 0; r < 4; ++r)
                C[(size_t)(rbase + r) * NDIM + col] = acc[i][j][r] + bs;
        }
    }
}

// ---------------------------------------------------------------------------
// Filt finish: tanh(t_g + fb) -> per-block LDS partials -> wacc atomics.
// ---------------------------------------------------------------------------
__global__ void filt_finish_k(const float* __restrict__ t_g, const float* __restrict__ fb,
                              float* __restrict__ wacc) {
    __shared__ float part[3];
    const int tid = threadIdx.x;
    if (tid < 3) part[tid] = 0.0f;
    __syncthreads();
    int p = blockIdx.x * 256 + tid;
    int row = p >> 1, f = p & 1;
    const float* tp = t_g + (size_t)row * 6 + f * 3;
    atomicAdd(&part[0], tanhf(tp[0] + fb[0]));
    atomicAdd(&part[1], tanhf(tp[1] + fb[1]));
    atomicAdd(&part[2], tanhf(tp[2] + fb[2]));
    __syncthreads();
    if (tid < 3) {
        int b = blockIdx.x >> 4;     // 16 blocks per batch
        atomicAdd(&wacc[b * 3 + tid], part[tid]);
    }
}

// ---------------------------------------------------------------------------
// Gate, strip-mined: g[r,d] = gelu(conv3_w(xs)[r,d] * v[r,d]), w = wacc/S.
// ---------------------------------------------------------------------------
__global__ void gate_k(const u16* __restrict__ xs, const float* __restrict__ v,
                       const float* __restrict__ wacc, u16* __restrict__ g) {
    const int c = blockIdx.x * 1024 + threadIdx.x * 4;
    const int r0 = blockIdx.y * STRIP;
    const int t0 = r0 & (S_ - 1);
    const int b = r0 >> 11;
    const float w0 = wacc[b * 3 + 0] * (1.0f / (float)S_);
    const float w1 = wacc[b * 3 + 1] * (1.0f / (float)S_);
    const float w2 = wacc[b * 3 + 2] * (1.0f / (float)S_);

    const u16* base = xs + (size_t)r0 * D_ + c;
    f32x4 m2, m1;
    if (t0 == 0) {
        m2 = (f32x4)(0.0f); m1 = (f32x4)(0.0f);
    } else {
        u16x4 a2 = *(const u16x4*)(base - 2 * D_);
        u16x4 a1 = *(const u16x4*)(base - D_);
        #pragma unroll
        for (int e = 0; e < 4; ++e) { m2[e] = b2f(a2[e]); m1[e] = b2f(a1[e]); }
    }

    const float* vp = v + (size_t)r0 * D_ + c;
    u16* op = g + (size_t)r0 * D_ + c;
    #pragma unroll
    for (int rr = 0; rr < STRIP; ++rr) {
        u16x4 cb = *(const u16x4*)(base + (size_t)rr * D_);
        f32x4 vv = *(const f32x4*)(vp + (size_t)rr * D_);
        f32x4 cur;
        #pragma unroll
        for (int e = 0; e < 4; ++e) cur[e] = b2f(cb[e]);
        u16x4 outv;
        #pragma unroll
        for (int e = 0; e < 4; ++e) {
            float conv = w0 * m2[e] + w1 * m1[e] + w2 * cur[e];
            outv[e] = f2b(gelu_exact(conv * vv[e]));
        }
        *(u16x4*)(op + (size_t)rr * D_) = outv;
        m2 = m1; m1 = cur;
    }
}

// ---------------------------------------------------------------------------
extern "C" void kernel_launch(void* const* d_in, const int* in_sizes, int n_in,
                              void* d_out, int out_size, void* d_ws, size_t ws_size,
                              hipStream_t stream) {
    const float* x       = (const float*)d_in[0];
    const float* short_w = (const float*)d_in[1];
    const float* short_b = (const float*)d_in[2];
    const float* proj_w  = (const float*)d_in[3];
    const float* proj_b  = (const float*)d_in[4];
    const float* filt_w  = (const float*)d_in[5];
    const float* filt_b  = (const float*)d_in[6];
    const float* out_w   = (const float*)d_in[7];
    const float* out_b   = (const float*)d_in[8];
    float* out = (float*)d_out;

    // ws: wacc | t_g | xs bf16 32MB | g bf16 32MB | wT1 8MB [| wT2 8MB]
    char* ws = (char*)d_ws;
    const size_t xs_bytes = (size_t)MROWS * D_ * 2;   // 33,554,432
    const size_t wt_bytes = (size_t)KDIM * NDIM * 2;  // 8,388,608
    float* wacc = (float*)(ws);
    float* t_g  = (float*)(ws + 1024);                // 8192*6 fp32
    u16*   xs   = (u16*)(ws + 262144);
    u16*   g    = (u16*)(ws + 262144 + xs_bytes);
    u16*   wT1  = (u16*)(ws + 262144 + 2 * xs_bytes);
    const size_t need_dual = 262144 + 2 * xs_bytes + 2 * wt_bytes;
    const bool dual = (ws_size >= need_dual);
    u16* wT2 = dual ? (u16*)(ws + 262144 + 2 * xs_bytes + wt_bytes) : wT1;

    dim3 tb(32, 8, 1);

    if (dual) {
        dim3 tg(D_ / 32, D_ / 32, 2);
        transpose_k<<<tg, tb, 0, stream>>>(proj_w, wT1, out_w, wT2, D_);
    } else {
        dim3 tg(D_ / 32, D_ / 32, 1);
        transpose_k<<<tg, tb, 0, stream>>>(proj_w, wT1, proj_w, wT1, D_);
    }

    dim3 cg(2, MROWS / STRIP, 1);   // 1024 blocks
    shortconv_k<<<cg, 256, 0, stream>>>(x, short_w, short_b, xs, wacc, t_g);

    dim3 gg(NDIM / 256, MROWS / 256, 1);     // (8, 32) = 256 blocks, 1/CU
    gemm_f8<<<gg, 512, 0, stream>>>(xs, wT1, proj_b, filt_w, t_g);

    filt_finish_k<<<64, 256, 0, stream>>>(t_g, filt_b, wacc);

    if (!dual) {
        dim3 tg(D_ / 32, D_ / 32, 1);
        transpose_k<<<tg, tb, 0, stream>>>(out_w, wT2, out_w, wT2, D_);
    }

    gate_k<<<cg, 256, 0, stream>>>(xs, x, wacc, g);

    gemm8_k<<<gg, 512, 0, stream>>>(g, wT2, out_b, out);
}

// Round 5
// 360.247 us; speedup vs baseline: 1.0127x; 1.0127x over previous
//
#include <hip/hip_runtime.h>
#include <hip/hip_bf16.h>
#include <math.h>

typedef unsigned short u16;
typedef __attribute__((ext_vector_type(4))) unsigned short u16x4;
typedef __attribute__((ext_vector_type(8))) unsigned short u16x8;
typedef __attribute__((ext_vector_type(8))) short s16x8;
typedef __attribute__((ext_vector_type(4))) float f32x4;

#define B_  4
#define S_  2048
#define D_  2048
#define DI_ 1024
#define MROWS (B_ * S_)          // 8192
#define KDIM  D_                 // 2048
#define NDIM  D_                 // 2048
#define STRIP 16                 // rows per conv strip (divides S_)

__device__ __forceinline__ float b2f(u16 u) {
    union { unsigned i; float f; } v; v.i = ((unsigned)u) << 16; return v.f;
}
__device__ __forceinline__ u16 f2b(float f) {
    unsigned u = __float_as_uint(f);
    unsigned r = (u + 0x7FFFu + ((u >> 16) & 1u)) >> 16;
    return (u16)r;
}
__device__ __forceinline__ float gelu_exact(float x) {
    return 0.5f * x * (1.0f + erff(x * 0.70710678118654752f));
}

#define GLOAD_LDS16(gp, lp)                                                    \
    __builtin_amdgcn_global_load_lds(                                          \
        (const __attribute__((address_space(1))) void*)(gp),                   \
        (__attribute__((address_space(3))) void*)(lp), 16, 0, 0)

// ---------------------------------------------------------------------------
// Transpose n x n, fp32 in -> bf16 out. blockIdx.z picks src/dst when dual.
// ---------------------------------------------------------------------------
__global__ void transpose_k(const float* __restrict__ in0, u16* __restrict__ out0,
                            const float* __restrict__ in1, u16* __restrict__ out1,
                            int n) {
    __shared__ float tile[32][33];
    const float* in = (blockIdx.z == 0) ? in0 : in1;
    u16* out = (blockIdx.z == 0) ? out0 : out1;
    int bx = blockIdx.x * 32, by = blockIdx.y * 32;
    int tx = threadIdx.x, ty = threadIdx.y;
    for (int i = 0; i < 32; i += 8)
        tile[ty + i][tx] = in[(size_t)(by + ty + i) * n + bx + tx];
    __syncthreads();
    for (int i = 0; i < 32; i += 8)
        out[(size_t)(bx + ty + i) * n + by + tx] = f2b(tile[tx][ty + i]);
}

// ---------------------------------------------------------------------------
// Short conv, strip-mined (fp32 in, bf16 out). Also zeroes wacc and t_g.
// ---------------------------------------------------------------------------
__global__ void shortconv_k(const float* __restrict__ x, const float* __restrict__ sw,
                            const float* __restrict__ sb, u16* __restrict__ xs,
                            float* __restrict__ wacc, float* __restrict__ t_g) {
    const int bid = blockIdx.y * 2 + blockIdx.x;
    {
        int z = bid * 256 + threadIdx.x;
        if (z < 12) wacc[z] = 0.0f;
        if (z < MROWS * 6) t_g[z] = 0.0f;
    }
    const int c = blockIdx.x * 1024 + threadIdx.x * 4;
    const int r0 = blockIdx.y * STRIP;
    const int t0 = r0 & (S_ - 1);

    float tap[12];
    #pragma unroll
    for (int q = 0; q < 3; ++q)
        ((f32x4*)tap)[q] = *(const f32x4*)(sw + (size_t)c * 3 + q * 4);
    f32x4 sbv = *(const f32x4*)(sb + c);

    const float* base = x + (size_t)r0 * D_ + c;
    f32x4 m2, m1;
    if (t0 == 0) { m2 = (f32x4)(0.0f); m1 = (f32x4)(0.0f); }
    else { m2 = *(const f32x4*)(base - 2 * D_); m1 = *(const f32x4*)(base - D_); }

    u16* op = xs + (size_t)r0 * D_ + c;
    #pragma unroll
    for (int rr = 0; rr < STRIP; ++rr) {
        f32x4 cur = *(const f32x4*)(base + (size_t)rr * D_);
        u16x4 outv;
        #pragma unroll
        for (int e = 0; e < 4; ++e) {
            float v = cur[e] + sbv[e]
                    + tap[e * 3 + 0] * m2[e]
                    + tap[e * 3 + 1] * m1[e]
                    + tap[e * 3 + 2] * cur[e];
            outv[e] = f2b(v);
        }
        *(u16x4*)(op + (size_t)rr * D_) = outv;
        m2 = m1; m1 = cur;
    }
}

// ===========================================================================
// Overlap core: 256x256 tile, BK=32 regions x4 (128 KiB LDS ring), 8 waves
// (2Mx4N), per-wave 128x64 output, acc[8][4] f32x4.
//
// READ-AHEAD pipeline (the round-5 change): fragment ds_reads are issued one
// MFMA-cluster AHEAD into double-buffered registers; NO explicit lgkmcnt —
// the compiler inserts minimal counted waits at the consuming MFMA, so LDS
// service of cluster N+1 overlaps the MFMA of cluster N.
//
// Per 32-k tile T (region R = T&3), two phases:
//  PH_A: BARR (WAR gate: all waves drained region (T-1) reads)
//        stage tile T+3 -> region (T+3)&3 == (T-1)&3  (4 global_load_lds)
//        issue aH(T) reads (4)            [region R]
//        MFMA acc[0..3] += aL(T) x bC(T)  [issued last phase -> slack]
//  PH_B: vmcnt(8)  (forces stage of tile T+1 landed; tiles T+2,T+3 = 8
//        loads may remain in flight), BARR (all waves' stages forced)
//        issue aL/bC(T+1) reads (8)       [region (T+1)&3]
//        MFMA acc[4..7] += aH(T) x bC(T)
// Hazards verified: restage region == (T-1)&3, whose reads (aH(T-1)) were
// drained before MFMA_HI(T-1), hence before this BARR. In-flight DMA
// regions {T+2,T+3}&3 disjoint from read regions {T,T+1}&3. Epilogue
// T=61/62/63: no stage; gates VM4/VM0/none.
// ===========================================================================
#define STG_A(REG, KOFF) do { const u16* _g = gA + (KOFF);                     \
    GLOAD_LDS16(_g, &As[REG][ldsW0]);                                          \
    GLOAD_LDS16(_g + (size_t)128 * KDIM, &As[REG][ldsW1]); } while (0)
#define STG_B(REG, KOFF) do { const u16* _g = gB + (KOFF);                     \
    GLOAD_LDS16(_g, &Bs[REG][ldsW0]);                                          \
    GLOAD_LDS16(_g + (size_t)128 * KDIM, &Bs[REG][ldsW1]); } while (0)
#define LD_AH(R_) do {                                                         \
    aH[0] = *(const s16x8*)&As[R_][aoffR[4]];                                  \
    aH[1] = *(const s16x8*)&As[R_][aoffR[5]];                                  \
    aH[2] = *(const s16x8*)&As[R_][aoffR[6]];                                  \
    aH[3] = *(const s16x8*)&As[R_][aoffR[7]]; } while (0)
#define LD_ALBC(S_, R_) do {                                                   \
    aL[S_][0] = *(const s16x8*)&As[R_][aoffR[0]];                              \
    aL[S_][1] = *(const s16x8*)&As[R_][aoffR[1]];                              \
    aL[S_][2] = *(const s16x8*)&As[R_][aoffR[2]];                              \
    aL[S_][3] = *(const s16x8*)&As[R_][aoffR[3]];                              \
    bC[S_][0] = *(const s16x8*)&Bs[R_][boffR[0]];                              \
    bC[S_][1] = *(const s16x8*)&Bs[R_][boffR[1]];                              \
    bC[S_][2] = *(const s16x8*)&Bs[R_][boffR[2]];                              \
    bC[S_][3] = *(const s16x8*)&Bs[R_][boffR[3]]; } while (0)
#define MFMA_LO(S_) do { __builtin_amdgcn_s_setprio(1);                        \
    _Pragma("unroll")                                                          \
    for (int i_ = 0; i_ < 4; ++i_) {                                           \
        _Pragma("unroll")                                                      \
        for (int j_ = 0; j_ < 4; ++j_)                                         \
            acc[i_][j_] = __builtin_amdgcn_mfma_f32_16x16x32_bf16(             \
                aL[S_][i_], bC[S_][j_], acc[i_][j_], 0, 0, 0);                 \
    }                                                                          \
    __builtin_amdgcn_s_setprio(0); } while (0)
#define MFMA_HI(S_) do { __builtin_amdgcn_s_setprio(1);                        \
    _Pragma("unroll")                                                          \
    for (int i_ = 0; i_ < 4; ++i_) {                                           \
        _Pragma("unroll")                                                      \
        for (int j_ = 0; j_ < 4; ++j_)                                         \
            acc[4 + i_][j_] = __builtin_amdgcn_mfma_f32_16x16x32_bf16(         \
                aH[i_], bC[S_][j_], acc[4 + i_][j_], 0, 0, 0);                 \
    }                                                                          \
    __builtin_amdgcn_s_setprio(0); } while (0)
#define BARR() __builtin_amdgcn_s_barrier()
#define VM8() asm volatile("s_waitcnt vmcnt(8)" ::: "memory")
#define VM4() asm volatile("s_waitcnt vmcnt(4)" ::: "memory")
#define VM0() asm volatile("s_waitcnt vmcnt(0)" ::: "memory")
#define VMNOP()

// TILE: R_ literal region of T; RN_ = (R_+1)&3 literal; CS_ current reg set
// (T&1), NS_ = CS_^1; DOSTG_ stage tile T+3; GATE_ vm gate; DOPF_ prefetch.
#define TILE(T_, R_, RN_, CS_, NS_, DOSTG_, GATE_, DOPF_) do {                 \
    BARR();                                                                    \
    if (DOSTG_) { STG_A((((R_) + 3) & 3), ((T_) + 3) * 32);                    \
                  STG_B((((R_) + 3) & 3), ((T_) + 3) * 32); }                  \
    LD_AH(R_);                                                                 \
    MFMA_LO(CS_);                                                              \
    GATE_;                                                                     \
    BARR();                                                                    \
    if (DOPF_) { LD_ALBC(NS_, RN_); }                                          \
    MFMA_HI(CS_);                                                              \
} while (0)

#define GEMM_CORE_OL(APTR, BPTR)                                               \
    __shared__ u16 As[4][8192];                                                \
    __shared__ u16 Bs[4][8192];                                                \
    const int tid  = threadIdx.x;                                              \
    const int wid  = tid >> 6;                                                 \
    const int lane = tid & 63;                                                 \
    const int wr   = wid >> 2;                                                 \
    const int wc   = wid & 3;                                                  \
    const int row0 = blockIdx.y << 8;                                          \
    const int col0 = blockIdx.x << 8;                                          \
    const int rowS    = tid >> 2;                                              \
    const int colOffS = (((tid & 3) ^ ((rowS >> 1) & 3)) << 3);                \
    const u16* gA = (APTR) + (size_t)(row0 + rowS) * KDIM + colOffS;           \
    const u16* gB = (BPTR) + (size_t)(col0 + rowS) * KDIM + colOffS;           \
    const int ldsW0 = wid * 512;                                               \
    const int ldsW1 = 4096 + wid * 512;                                        \
    int aoffR[8], boffR[4];                                                    \
    _Pragma("unroll")                                                          \
    for (int i = 0; i < 8; ++i) {                                              \
        int row  = (wr << 7) + (i << 4) + (lane & 15);                         \
        int slot = (lane >> 4) ^ ((row >> 1) & 3);                             \
        aoffR[i] = row * 32 + slot * 8;                                        \
    }                                                                          \
    _Pragma("unroll")                                                          \
    for (int j = 0; j < 4; ++j) {                                              \
        int row  = (wc << 6) + (j << 4) + (lane & 15);                         \
        int slot = (lane >> 4) ^ ((row >> 1) & 3);                             \
        boffR[j] = row * 32 + slot * 8;                                        \
    }                                                                          \
    f32x4 acc[8][4];                                                           \
    _Pragma("unroll")                                                          \
    for (int i = 0; i < 8; ++i)                                                \
        _Pragma("unroll")                                                      \
        for (int j = 0; j < 4; ++j) acc[i][j] = (f32x4)(0.0f);                 \
    s16x8 aL[2][4], bC[2][4], aH[4];                                           \
    STG_A(0, 0);  STG_B(0, 0);                                                 \
    STG_A(1, 32); STG_B(1, 32);                                                \
    STG_A(2, 64); STG_B(2, 64);                                                \
    VM8();                        /* region 0 landed (tiles 1,2 in flight) */  \
    BARR();                                                                    \
    LD_ALBC(0, 0);                /* aL/bC for tile 0 */                       \
    _Pragma("unroll 1")                                                        \
    for (int t = 0; t < 15; ++t) {                                             \
        const int T4 = t * 4;                                                  \
        TILE(T4 + 0, 0, 1, 0, 1, 1, VM8(), 1);                                 \
        TILE(T4 + 1, 1, 2, 1, 0, 1, VM8(), 1);                                 \
        TILE(T4 + 2, 2, 3, 0, 1, 1, VM8(), 1);                                 \
        TILE(T4 + 3, 3, 0, 1, 0, 1, VM8(), 1);                                 \
    }                                                                          \
    TILE(60, 0, 1, 0, 1, 1, VM8(), 1);                                         \
    TILE(61, 1, 2, 1, 0, 0, VM4(), 1);                                         \
    TILE(62, 2, 3, 0, 1, 0, VM0(), 1);                                         \
    TILE(63, 3, 0, 1, 0, 0, VMNOP(), 0);

// ---------------------------------------------------------------------------
// GEMM1 (FILT): epilogue folds gelu(acc+bias)*fw into t_g partials.
// ---------------------------------------------------------------------------
__global__ __launch_bounds__(512, 2)
void gemm_f8(const u16* __restrict__ A, const u16* __restrict__ BT,
             const float* __restrict__ bias,
             const float* __restrict__ fw, float* __restrict__ t_g) {
    GEMM_CORE_OL(A, BT)

    __shared__ float t_lds[768];
    __syncthreads();
    for (int z = tid; z < 768; z += 512) t_lds[z] = 0.0f;
    __syncthreads();

    const int colt0 = (wc << 6) + (lane & 15);
    float fwv[4][3], bsv[4];
    const int ibase = (col0 & (DI_ - 1)) + colt0;
    #pragma unroll
    for (int j = 0; j < 4; ++j) {
        int ifilt = ibase + j * 16;
        fwv[j][0] = fw[ifilt * 3 + 0];
        fwv[j][1] = fw[ifilt * 3 + 1];
        fwv[j][2] = fw[ifilt * 3 + 2];
        bsv[j] = bias[col0 + colt0 + j * 16];
    }
    #pragma unroll
    for (int i = 0; i < 8; ++i) {
        #pragma unroll
        for (int r = 0; r < 4; ++r) {
            float s0 = 0.f, s1 = 0.f, s2 = 0.f;
            #pragma unroll
            for (int j = 0; j < 4; ++j) {
                float hv = gelu_exact(acc[i][j][r] + bsv[j]);
                s0 += hv * fwv[j][0];
                s1 += hv * fwv[j][1];
                s2 += hv * fwv[j][2];
            }
            #pragma unroll
            for (int m = 1; m < 16; m <<= 1) {
                s0 += __shfl_xor(s0, m, 16);
                s1 += __shfl_xor(s1, m, 16);
                s2 += __shfl_xor(s2, m, 16);
            }
            if ((lane & 15) == 0) {
                int trow = (wr << 7) + ((lane >> 4) << 2) + (i << 4) + r;
                atomicAdd(&t_lds[trow * 3 + 0], s0);
                atomicAdd(&t_lds[trow * 3 + 1], s1);
                atomicAdd(&t_lds[trow * 3 + 2], s2);
            }
        }
    }
    __syncthreads();
    const int f3 = (col0 >= DI_) ? 3 : 0;
    for (int z = tid; z < 768; z += 512) {
        int rr = z / 3, k = z - rr * 3;
        atomicAdd(&t_g[(size_t)(row0 + rr) * 6 + f3 + k], t_lds[z]);
    }
}

// ---------------------------------------------------------------------------
// GEMM2 (plain): C fp32 = acc + bias.
// ---------------------------------------------------------------------------
__global__ __launch_bounds__(512, 2)
void gemm8_k(const u16* __restrict__ A, const u16* __restrict__ BT,
             const float* __restrict__ bias, float* __restrict__ C) {
    GEMM_CORE_OL(A, BT)

    const int colt0 = (wc << 6) + (lane & 15);
    const int crow0 = row0 + (wr << 7) + ((lane >> 4) << 2);
    #pragma unroll
    for (int j = 0; j < 4; ++j) {
        int col = col0 + colt0 + j * 16;
        float bs = bias[col];
        #pragma unroll
        for (int i = 0; i < 8; ++i) {
            int rbase = crow0 + i * 16;
            #pragma unroll
            for (int r = 0; r < 4; ++r)
                C[(size_t)(rbase + r) * NDIM + col] = acc[i][j][r] + bs;
        }
    }
}

// ---------------------------------------------------------------------------
// Filt finish: tanh(t_g + fb) -> per-block LDS partials -> wacc atomics.
// ---------------------------------------------------------------------------
__global__ void filt_finish_k(const float* __restrict__ t_g, const float* __restrict__ fb,
                              float* __restrict__ wacc) {
    __shared__ float part[3];
    const int tid = threadIdx.x;
    if (tid < 3) part[tid] = 0.0f;
    __syncthreads();
    int p = blockIdx.x * 256 + tid;
    int row = p >> 1, f = p & 1;
    const float* tp = t_g + (size_t)row * 6 + f * 3;
    atomicAdd(&part[0], tanhf(tp[0] + fb[0]));
    atomicAdd(&part[1], tanhf(tp[1] + fb[1]));
    atomicAdd(&part[2], tanhf(tp[2] + fb[2]));
    __syncthreads();
    if (tid < 3) {
        int b = blockIdx.x >> 4;     // 16 blocks per batch
        atomicAdd(&wacc[b * 3 + tid], part[tid]);
    }
}

// ---------------------------------------------------------------------------
// Gate, strip-mined: g[r,d] = gelu(conv3_w(xs)[r,d] * v[r,d]), w = wacc/S.
// ---------------------------------------------------------------------------
__global__ void gate_k(const u16* __restrict__ xs, const float* __restrict__ v,
                       const float* __restrict__ wacc, u16* __restrict__ g) {
    const int c = blockIdx.x * 1024 + threadIdx.x * 4;
    const int r0 = blockIdx.y * STRIP;
    const int t0 = r0 & (S_ - 1);
    const int b = r0 >> 11;
    const float w0 = wacc[b * 3 + 0] * (1.0f / (float)S_);
    const float w1 = wacc[b * 3 + 1] * (1.0f / (float)S_);
    const float w2 = wacc[b * 3 + 2] * (1.0f / (float)S_);

    const u16* base = xs + (size_t)r0 * D_ + c;
    f32x4 m2, m1;
    if (t0 == 0) {
        m2 = (f32x4)(0.0f); m1 = (f32x4)(0.0f);
    } else {
        u16x4 a2 = *(const u16x4*)(base - 2 * D_);
        u16x4 a1 = *(const u16x4*)(base - D_);
        #pragma unroll
        for (int e = 0; e < 4; ++e) { m2[e] = b2f(a2[e]); m1[e] = b2f(a1[e]); }
    }

    const float* vp = v + (size_t)r0 * D_ + c;
    u16* op = g + (size_t)r0 * D_ + c;
    #pragma unroll
    for (int rr = 0; rr < STRIP; ++rr) {
        u16x4 cb = *(const u16x4*)(base + (size_t)rr * D_);
        f32x4 vv = *(const f32x4*)(vp + (size_t)rr * D_);
        f32x4 cur;
        #pragma unroll
        for (int e = 0; e < 4; ++e) cur[e] = b2f(cb[e]);
        u16x4 outv;
        #pragma unroll
        for (int e = 0; e < 4; ++e) {
            float conv = w0 * m2[e] + w1 * m1[e] + w2 * cur[e];
            outv[e] = f2b(gelu_exact(conv * vv[e]));
        }
        *(u16x4*)(op + (size_t)rr * D_) = outv;
        m2 = m1; m1 = cur;
    }
}

// ---------------------------------------------------------------------------
extern "C" void kernel_launch(void* const* d_in, const int* in_sizes, int n_in,
                              void* d_out, int out_size, void* d_ws, size_t ws_size,
                              hipStream_t stream) {
    const float* x       = (const float*)d_in[0];
    const float* short_w = (const float*)d_in[1];
    const float* short_b = (const float*)d_in[2];
    const float* proj_w  = (const float*)d_in[3];
    const float* proj_b  = (const float*)d_in[4];
    const float* filt_w  = (const float*)d_in[5];
    const float* filt_b  = (const float*)d_in[6];
    const float* out_w   = (const float*)d_in[7];
    const float* out_b   = (const float*)d_in[8];
    float* out = (float*)d_out;

    // ws: wacc | t_g | xs bf16 32MB | g bf16 32MB | wT1 8MB [| wT2 8MB]
    char* ws = (char*)d_ws;
    const size_t xs_bytes = (size_t)MROWS * D_ * 2;   // 33,554,432
    const size_t wt_bytes = (size_t)KDIM * NDIM * 2;  // 8,388,608
    float* wacc = (float*)(ws);
    float* t_g  = (float*)(ws + 1024);                // 8192*6 fp32
    u16*   xs   = (u16*)(ws + 262144);
    u16*   g    = (u16*)(ws + 262144 + xs_bytes);
    u16*   wT1  = (u16*)(ws + 262144 + 2 * xs_bytes);
    const size_t need_dual = 262144 + 2 * xs_bytes + 2 * wt_bytes;
    const bool dual = (ws_size >= need_dual);
    u16* wT2 = dual ? (u16*)(ws + 262144 + 2 * xs_bytes + wt_bytes) : wT1;

    dim3 tb(32, 8, 1);

    if (dual) {
        dim3 tg(D_ / 32, D_ / 32, 2);
        transpose_k<<<tg, tb, 0, stream>>>(proj_w, wT1, out_w, wT2, D_);
    } else {
        dim3 tg(D_ / 32, D_ / 32, 1);
        transpose_k<<<tg, tb, 0, stream>>>(proj_w, wT1, proj_w, wT1, D_);
    }

    dim3 cg(2, MROWS / STRIP, 1);   // 1024 blocks
    shortconv_k<<<cg, 256, 0, stream>>>(x, short_w, short_b, xs, wacc, t_g);

    dim3 gg(NDIM / 256, MROWS / 256, 1);     // (8, 32) = 256 blocks, 1/CU
    gemm_f8<<<gg, 512, 0, stream>>>(xs, wT1, proj_b, filt_w, t_g);

    filt_finish_k<<<64, 256, 0, stream>>>(t_g, filt_b, wacc);

    if (!dual) {
        dim3 tg(D_ / 32, D_ / 32, 1);
        transpose_k<<<tg, tb, 0, stream>>>(out_w, wT2, out_w, wT2, D_);
    }

    gate_k<<<cg, 256, 0, stream>>>(xs, x, wacc, g);

    gemm8_k<<<gg, 512, 0, stream>>>(g, wT2, out_b, out);
}

// Round 6
// 354.637 us; speedup vs baseline: 1.0288x; 1.0158x over previous
//
#include <hip/hip_runtime.h>
#include <hip/hip_bf16.h>
#include <math.h>

typedef unsigned short u16;
typedef __attribute__((ext_vector_type(4))) unsigned short u16x4;
typedef __attribute__((ext_vector_type(8))) unsigned short u16x8;
typedef __attribute__((ext_vector_type(8))) short s16x8;
typedef __attribute__((ext_vector_type(4))) float f32x4;

#define B_  4
#define S_  2048
#define D_  2048
#define DI_ 1024
#define MROWS (B_ * S_)          // 8192
#define KDIM  D_                 // 2048
#define NDIM  D_                 // 2048
#define STRIP 16                 // rows per conv strip (divides S_)

__device__ __forceinline__ float b2f(u16 u) {
    union { unsigned i; float f; } v; v.i = ((unsigned)u) << 16; return v.f;
}
__device__ __forceinline__ u16 f2b(float f) {
    unsigned u = __float_as_uint(f);
    unsigned r = (u + 0x7FFFu + ((u >> 16) & 1u)) >> 16;
    return (u16)r;
}
__device__ __forceinline__ float gelu_exact(float x) {
    return 0.5f * x * (1.0f + erff(x * 0.70710678118654752f));
}

#define GLOAD_LDS16(gp, lp)                                                    \
    __builtin_amdgcn_global_load_lds(                                          \
        (const __attribute__((address_space(1))) void*)(gp),                   \
        (__attribute__((address_space(3))) void*)(lp), 16, 0, 0)

// ---------------------------------------------------------------------------
// Transpose n x n, fp32 in -> bf16 out. blockIdx.z picks src/dst when dual.
// ---------------------------------------------------------------------------
__global__ void transpose_k(const float* __restrict__ in0, u16* __restrict__ out0,
                            const float* __restrict__ in1, u16* __restrict__ out1,
                            int n) {
    __shared__ float tile[32][33];
    const float* in = (blockIdx.z == 0) ? in0 : in1;
    u16* out = (blockIdx.z == 0) ? out0 : out1;
    int bx = blockIdx.x * 32, by = blockIdx.y * 32;
    int tx = threadIdx.x, ty = threadIdx.y;
    for (int i = 0; i < 32; i += 8)
        tile[ty + i][tx] = in[(size_t)(by + ty + i) * n + bx + tx];
    __syncthreads();
    for (int i = 0; i < 32; i += 8)
        out[(size_t)(bx + ty + i) * n + by + tx] = f2b(tile[tx][ty + i]);
}

// ---------------------------------------------------------------------------
// Short conv, strip-mined (fp32 in, bf16 out). Also zeroes wacc and t_g.
// ---------------------------------------------------------------------------
__global__ void shortconv_k(const float* __restrict__ x, const float* __restrict__ sw,
                            const float* __restrict__ sb, u16* __restrict__ xs,
                            float* __restrict__ wacc, float* __restrict__ t_g) {
    const int bid = blockIdx.y * 2 + blockIdx.x;
    {
        int z = bid * 256 + threadIdx.x;
        if (z < 12) wacc[z] = 0.0f;
        if (z < MROWS * 6) t_g[z] = 0.0f;
    }
    const int c = blockIdx.x * 1024 + threadIdx.x * 4;
    const int r0 = blockIdx.y * STRIP;
    const int t0 = r0 & (S_ - 1);

    float tap[12];
    #pragma unroll
    for (int q = 0; q < 3; ++q)
        ((f32x4*)tap)[q] = *(const f32x4*)(sw + (size_t)c * 3 + q * 4);
    f32x4 sbv = *(const f32x4*)(sb + c);

    const float* base = x + (size_t)r0 * D_ + c;
    f32x4 m2, m1;
    if (t0 == 0) { m2 = (f32x4)(0.0f); m1 = (f32x4)(0.0f); }
    else { m2 = *(const f32x4*)(base - 2 * D_); m1 = *(const f32x4*)(base - D_); }

    u16* op = xs + (size_t)r0 * D_ + c;
    #pragma unroll
    for (int rr = 0; rr < STRIP; ++rr) {
        f32x4 cur = *(const f32x4*)(base + (size_t)rr * D_);
        u16x4 outv;
        #pragma unroll
        for (int e = 0; e < 4; ++e) {
            float v = cur[e] + sbv[e]
                    + tap[e * 3 + 0] * m2[e]
                    + tap[e * 3 + 1] * m1[e]
                    + tap[e * 3 + 2] * cur[e];
            outv[e] = f2b(v);
        }
        *(u16x4*)(op + (size_t)rr * D_) = outv;
        m2 = m1; m1 = cur;
    }
}

// ===========================================================================
// OL core (proven, round-5): 256x256 tile, BK=32 regions x4, 8 waves,
// read-ahead register dbuf. Round-6 change: XCD-aware bijective block
// swizzle (nwg=256=8x32): XCD k gets 32 contiguous works = 4 A-row-panels
// x all 8 col-blocks -> A-panel sharing becomes intra-XCD L2 (was cross-XCD
// via L3). Per-XCD L2 fill 33MB -> 12MB.
// ===========================================================================
#define STG_A(REG, KOFF) do { const u16* _g = gA + (KOFF);                     \
    GLOAD_LDS16(_g, &As[REG][ldsW0]);                                          \
    GLOAD_LDS16(_g + (size_t)128 * KDIM, &As[REG][ldsW1]); } while (0)
#define STG_B(REG, KOFF) do { const u16* _g = gB + (KOFF);                     \
    GLOAD_LDS16(_g, &Bs[REG][ldsW0]);                                          \
    GLOAD_LDS16(_g + (size_t)128 * KDIM, &Bs[REG][ldsW1]); } while (0)
#define LD_AH(R_) do {                                                         \
    aH[0] = *(const s16x8*)&As[R_][aoffR[4]];                                  \
    aH[1] = *(const s16x8*)&As[R_][aoffR[5]];                                  \
    aH[2] = *(const s16x8*)&As[R_][aoffR[6]];                                  \
    aH[3] = *(const s16x8*)&As[R_][aoffR[7]]; } while (0)
#define LD_ALBC(S_, R_) do {                                                   \
    aL[S_][0] = *(const s16x8*)&As[R_][aoffR[0]];                              \
    aL[S_][1] = *(const s16x8*)&As[R_][aoffR[1]];                              \
    aL[S_][2] = *(const s16x8*)&As[R_][aoffR[2]];                              \
    aL[S_][3] = *(const s16x8*)&As[R_][aoffR[3]];                              \
    bC[S_][0] = *(const s16x8*)&Bs[R_][boffR[0]];                              \
    bC[S_][1] = *(const s16x8*)&Bs[R_][boffR[1]];                              \
    bC[S_][2] = *(const s16x8*)&Bs[R_][boffR[2]];                              \
    bC[S_][3] = *(const s16x8*)&Bs[R_][boffR[3]]; } while (0)
#define MFMA_LO(S_) do { __builtin_amdgcn_s_setprio(1);                        \
    _Pragma("unroll")                                                          \
    for (int i_ = 0; i_ < 4; ++i_) {                                           \
        _Pragma("unroll")                                                      \
        for (int j_ = 0; j_ < 4; ++j_)                                         \
            acc[i_][j_] = __builtin_amdgcn_mfma_f32_16x16x32_bf16(             \
                aL[S_][i_], bC[S_][j_], acc[i_][j_], 0, 0, 0);                 \
    }                                                                          \
    __builtin_amdgcn_s_setprio(0); } while (0)
#define MFMA_HI(S_) do { __builtin_amdgcn_s_setprio(1);                        \
    _Pragma("unroll")                                                          \
    for (int i_ = 0; i_ < 4; ++i_) {                                           \
        _Pragma("unroll")                                                      \
        for (int j_ = 0; j_ < 4; ++j_)                                         \
            acc[4 + i_][j_] = __builtin_amdgcn_mfma_f32_16x16x32_bf16(         \
                aH[i_], bC[S_][j_], acc[4 + i_][j_], 0, 0, 0);                 \
    }                                                                          \
    __builtin_amdgcn_s_setprio(0); } while (0)
#define BARR() __builtin_amdgcn_s_barrier()
#define VM8() asm volatile("s_waitcnt vmcnt(8)" ::: "memory")
#define VM4() asm volatile("s_waitcnt vmcnt(4)" ::: "memory")
#define VM0() asm volatile("s_waitcnt vmcnt(0)" ::: "memory")
#define VMNOP()

#define TILE(T_, R_, RN_, CS_, NS_, DOSTG_, GATE_, DOPF_) do {                 \
    BARR();                                                                    \
    if (DOSTG_) { STG_A((((R_) + 3) & 3), ((T_) + 3) * 32);                    \
                  STG_B((((R_) + 3) & 3), ((T_) + 3) * 32); }                  \
    LD_AH(R_);                                                                 \
    MFMA_LO(CS_);                                                              \
    GATE_;                                                                     \
    BARR();                                                                    \
    if (DOPF_) { LD_ALBC(NS_, RN_); }                                          \
    MFMA_HI(CS_);                                                              \
} while (0)

#define GEMM_CORE_OL(APTR, BPTR)                                               \
    __shared__ u16 As[4][8192];                                                \
    __shared__ u16 Bs[4][8192];                                                \
    const int tid  = threadIdx.x;                                              \
    const int wid  = tid >> 6;                                                 \
    const int lane = tid & 63;                                                 \
    const int wr   = wid >> 2;                                                 \
    const int wc   = wid & 3;                                                  \
    const int lid_ = (blockIdx.y << 3) | blockIdx.x;                           \
    const int wsw_ = ((lid_ & 7) << 5) | (lid_ >> 3);  /* xcd*32+slot */       \
    const int row0 = (wsw_ >> 3) << 8;                                         \
    const int col0 = (wsw_ & 7) << 8;                                          \
    const int rowS    = tid >> 2;                                              \
    const int colOffS = (((tid & 3) ^ ((rowS >> 1) & 3)) << 3);                \
    const u16* gA = (APTR) + (size_t)(row0 + rowS) * KDIM + colOffS;           \
    const u16* gB = (BPTR) + (size_t)(col0 + rowS) * KDIM + colOffS;           \
    const int ldsW0 = wid * 512;                                               \
    const int ldsW1 = 4096 + wid * 512;                                        \
    int aoffR[8], boffR[4];                                                    \
    _Pragma("unroll")                                                          \
    for (int i = 0; i < 8; ++i) {                                              \
        int row  = (wr << 7) + (i << 4) + (lane & 15);                         \
        int slot = (lane >> 4) ^ ((row >> 1) & 3);                             \
        aoffR[i] = row * 32 + slot * 8;                                        \
    }                                                                          \
    _Pragma("unroll")                                                          \
    for (int j = 0; j < 4; ++j) {                                              \
        int row  = (wc << 6) + (j << 4) + (lane & 15);                         \
        int slot = (lane >> 4) ^ ((row >> 1) & 3);                             \
        boffR[j] = row * 32 + slot * 8;                                        \
    }                                                                          \
    f32x4 acc[8][4];                                                           \
    _Pragma("unroll")                                                          \
    for (int i = 0; i < 8; ++i)                                                \
        _Pragma("unroll")                                                      \
        for (int j = 0; j < 4; ++j) acc[i][j] = (f32x4)(0.0f);                 \
    s16x8 aL[2][4], bC[2][4], aH[4];                                           \
    STG_A(0, 0);  STG_B(0, 0);                                                 \
    STG_A(1, 32); STG_B(1, 32);                                                \
    STG_A(2, 64); STG_B(2, 64);                                                \
    VM8();                                                                     \
    BARR();                                                                    \
    LD_ALBC(0, 0);                                                             \
    _Pragma("unroll 1")                                                        \
    for (int t = 0; t < 15; ++t) {                                             \
        const int T4 = t * 4;                                                  \
        TILE(T4 + 0, 0, 1, 0, 1, 1, VM8(), 1);                                 \
        TILE(T4 + 1, 1, 2, 1, 0, 1, VM8(), 1);                                 \
        TILE(T4 + 2, 2, 3, 0, 1, 1, VM8(), 1);                                 \
        TILE(T4 + 3, 3, 0, 1, 0, 1, VM8(), 1);                                 \
    }                                                                          \
    TILE(60, 0, 1, 0, 1, 1, VM8(), 1);                                         \
    TILE(61, 1, 2, 1, 0, 0, VM4(), 1);                                         \
    TILE(62, 2, 3, 0, 1, 0, VM0(), 1);                                         \
    TILE(63, 3, 0, 1, 0, 0, VMNOP(), 0);

// ---------------------------------------------------------------------------
// GEMM1 (FILT): OL core + XCD swizzle; epilogue folds gelu(acc+bias)*fw
// into t_g partials.
// ---------------------------------------------------------------------------
__global__ __launch_bounds__(512, 2)
void gemm_f8(const u16* __restrict__ A, const u16* __restrict__ BT,
             const float* __restrict__ bias,
             const float* __restrict__ fw, float* __restrict__ t_g) {
    GEMM_CORE_OL(A, BT)

    __shared__ float t_lds[768];
    __syncthreads();
    for (int z = tid; z < 768; z += 512) t_lds[z] = 0.0f;
    __syncthreads();

    const int colt0 = (wc << 6) + (lane & 15);
    float fwv[4][3], bsv[4];
    const int ibase = (col0 & (DI_ - 1)) + colt0;
    #pragma unroll
    for (int j = 0; j < 4; ++j) {
        int ifilt = ibase + j * 16;
        fwv[j][0] = fw[ifilt * 3 + 0];
        fwv[j][1] = fw[ifilt * 3 + 1];
        fwv[j][2] = fw[ifilt * 3 + 2];
        bsv[j] = bias[col0 + colt0 + j * 16];
    }
    #pragma unroll
    for (int i = 0; i < 8; ++i) {
        #pragma unroll
        for (int r = 0; r < 4; ++r) {
            float s0 = 0.f, s1 = 0.f, s2 = 0.f;
            #pragma unroll
            for (int j = 0; j < 4; ++j) {
                float hv = gelu_exact(acc[i][j][r] + bsv[j]);
                s0 += hv * fwv[j][0];
                s1 += hv * fwv[j][1];
                s2 += hv * fwv[j][2];
            }
            #pragma unroll
            for (int m = 1; m < 16; m <<= 1) {
                s0 += __shfl_xor(s0, m, 16);
                s1 += __shfl_xor(s1, m, 16);
                s2 += __shfl_xor(s2, m, 16);
            }
            if ((lane & 15) == 0) {
                int trow = (wr << 7) + ((lane >> 4) << 2) + (i << 4) + r;
                atomicAdd(&t_lds[trow * 3 + 0], s0);
                atomicAdd(&t_lds[trow * 3 + 1], s1);
                atomicAdd(&t_lds[trow * 3 + 2], s2);
            }
        }
    }
    __syncthreads();
    const int f3 = (col0 >= DI_) ? 3 : 0;
    for (int z = tid; z < 768; z += 512) {
        int rr = z / 3, k = z - rr * 3;
        atomicAdd(&t_g[(size_t)(row0 + rr) * 6 + f3 + k], t_lds[z]);
    }
}

// ---------------------------------------------------------------------------
// GEMM2 (plain), TLP arm: 256x128 tile, 256 thr / 4 waves (2Mx2N), per-wave
// 128x64 (acc[8][4], same fragment geometry as OL core), BK=32 dbuf
// (48 KiB LDS -> 2 blocks/CU at <=256 regs), simple stage-ahead + vmcnt(0)
// loop. Grid 512 blocks, XCD-swizzled (nwg=512=8x64). Mechanism under test:
// co-resident block hides the other's vmcnt/barrier drain (m114 TLP).
// ---------------------------------------------------------------------------
__global__ __launch_bounds__(256, 2)
void gemm2_tlp(const u16* __restrict__ A, const u16* __restrict__ BT,
               const float* __restrict__ bias, float* __restrict__ C) {
    __shared__ u16 As[2][8192];   // 256 rows x 32 k per region
    __shared__ u16 Bs[2][4096];   // 128 rows x 32 k per region

    const int tid  = threadIdx.x;          // 0..255
    const int wid  = tid >> 6;             // 0..3
    const int lane = tid & 63;
    const int wr   = wid >> 1;             // 0..1 : 128-row half
    const int wc   = wid & 1;              // 0..1 : 64-col half
    const int lid  = (blockIdx.y << 4) | blockIdx.x;      // 0..511, grid (16,32)
    const int wsw  = ((lid & 7) << 6) | (lid >> 3);       // xcd*64 + slot
    const int row0 = (wsw >> 4) << 8;      // by*256 (0..7936)
    const int col0 = (wsw & 15) << 7;      // bx*128 (0..1920)

    // staging: srow 0..63 per q-step; chunk swizzle (q*64 preserves (row>>1)&3)
    const int srow = tid >> 2;
    const int cSw  = (((tid & 3) ^ ((srow >> 1) & 3)) << 3);
    const u16* gA0 = A  + (size_t)(row0 + srow) * KDIM + cSw;
    const u16* gB0 = BT + (size_t)(col0 + srow) * KDIM + cSw;
    const int ldsW = wid * 512;            // u16 units within a q-slab

#define STG2(R_, KOFF) do {                                                    \
    const u16* _ga = gA0 + (KOFF);                                             \
    const u16* _gb = gB0 + (KOFF);                                             \
    GLOAD_LDS16(_ga,                     &As[R_][ldsW]);                       \
    GLOAD_LDS16(_ga + (size_t)64 * KDIM, &As[R_][2048 + ldsW]);                \
    GLOAD_LDS16(_ga + (size_t)128 * KDIM, &As[R_][4096 + ldsW]);               \
    GLOAD_LDS16(_ga + (size_t)192 * KDIM, &As[R_][6144 + ldsW]);               \
    GLOAD_LDS16(_gb,                     &Bs[R_][ldsW]);                       \
    GLOAD_LDS16(_gb + (size_t)64 * KDIM, &Bs[R_][2048 + ldsW]);                \
} while (0)

    int aoffR[8], boffR[4];
    #pragma unroll
    for (int i = 0; i < 8; ++i) {
        int row  = (wr << 7) + (i << 4) + (lane & 15);
        int slot = (lane >> 4) ^ ((row >> 1) & 3);
        aoffR[i] = row * 32 + slot * 8;
    }
    #pragma unroll
    for (int j = 0; j < 4; ++j) {
        int row  = (wc << 6) + (j << 4) + (lane & 15);
        int slot = (lane >> 4) ^ ((row >> 1) & 3);
        boffR[j] = row * 32 + slot * 8;
    }

    f32x4 acc[8][4];
    #pragma unroll
    for (int i = 0; i < 8; ++i)
        #pragma unroll
        for (int j = 0; j < 4; ++j) acc[i][j] = (f32x4)(0.0f);

    STG2(0, 0);
    VM0();
    BARR();

    #pragma unroll 1
    for (int T = 0; T < 64; ++T) {
        const int cur = T & 1;
        if (T < 63) STG2(cur ^ 1, (T + 1) * 32);
        s16x8 af[8], bf[4];
        #pragma unroll
        for (int i = 0; i < 8; ++i) af[i] = *(const s16x8*)&As[cur][aoffR[i]];
        #pragma unroll
        for (int j = 0; j < 4; ++j) bf[j] = *(const s16x8*)&Bs[cur][boffR[j]];
        __builtin_amdgcn_s_setprio(1);
        #pragma unroll
        for (int i = 0; i < 8; ++i)
            #pragma unroll
            for (int j = 0; j < 4; ++j)
                acc[i][j] = __builtin_amdgcn_mfma_f32_16x16x32_bf16(
                    af[i], bf[j], acc[i][j], 0, 0, 0);
        __builtin_amdgcn_s_setprio(0);
        VM0();
        BARR();
    }
#undef STG2

    // C write: row = row0 + wr*128 + (lane>>4)*4 + i*16 + r,
    //          col = col0 + wc*64 + (lane&15) + j*16
    const int colt0 = (wc << 6) + (lane & 15);
    const int crow0 = row0 + (wr << 7) + ((lane >> 4) << 2);
    #pragma unroll
    for (int j = 0; j < 4; ++j) {
        int col = col0 + colt0 + j * 16;
        float bs = bias[col];
        #pragma unroll
        for (int i = 0; i < 8; ++i) {
            int rbase = crow0 + i * 16;
            #pragma unroll
            for (int r = 0; r < 4; ++r)
                C[(size_t)(rbase + r) * NDIM + col] = acc[i][j][r] + bs;
        }
    }
}

// ---------------------------------------------------------------------------
// Filt finish: tanh(t_g + fb), wave shuffle-reduce (was 768 serialized LDS
// atomics/block), 4-wave LDS combine, 3 global atomics per block.
// ---------------------------------------------------------------------------
__global__ void filt_finish_k(const float* __restrict__ t_g, const float* __restrict__ fb,
                              float* __restrict__ wacc) {
    __shared__ float part[4][3];
    const int tid = threadIdx.x;
    int p = blockIdx.x * 256 + tid;
    int row = p >> 1, f = p & 1;
    const float* tp = t_g + (size_t)row * 6 + f * 3;
    float v0 = tanhf(tp[0] + fb[0]);
    float v1 = tanhf(tp[1] + fb[1]);
    float v2 = tanhf(tp[2] + fb[2]);
    #pragma unroll
    for (int m = 1; m < 64; m <<= 1) {
        v0 += __shfl_xor(v0, m, 64);
        v1 += __shfl_xor(v1, m, 64);
        v2 += __shfl_xor(v2, m, 64);
    }
    const int wid = tid >> 6, lane = tid & 63;
    if (lane == 0) { part[wid][0] = v0; part[wid][1] = v1; part[wid][2] = v2; }
    __syncthreads();
    if (tid < 3) {
        float s = part[0][tid] + part[1][tid] + part[2][tid] + part[3][tid];
        int b = blockIdx.x >> 4;     // 16 blocks per batch
        atomicAdd(&wacc[b * 3 + tid], s);
    }
}

// ---------------------------------------------------------------------------
// Gate, strip-mined: g[r,d] = gelu(conv3_w(xs)[r,d] * v[r,d]), w = wacc/S.
// ---------------------------------------------------------------------------
__global__ void gate_k(const u16* __restrict__ xs, const float* __restrict__ v,
                       const float* __restrict__ wacc, u16* __restrict__ g) {
    const int c = blockIdx.x * 1024 + threadIdx.x * 4;
    const int r0 = blockIdx.y * STRIP;
    const int t0 = r0 & (S_ - 1);
    const int b = r0 >> 11;
    const float w0 = wacc[b * 3 + 0] * (1.0f / (float)S_);
    const float w1 = wacc[b * 3 + 1] * (1.0f / (float)S_);
    const float w2 = wacc[b * 3 + 2] * (1.0f / (float)S_);

    const u16* base = xs + (size_t)r0 * D_ + c;
    f32x4 m2, m1;
    if (t0 == 0) {
        m2 = (f32x4)(0.0f); m1 = (f32x4)(0.0f);
    } else {
        u16x4 a2 = *(const u16x4*)(base - 2 * D_);
        u16x4 a1 = *(const u16x4*)(base - D_);
        #pragma unroll
        for (int e = 0; e < 4; ++e) { m2[e] = b2f(a2[e]); m1[e] = b2f(a1[e]); }
    }

    const float* vp = v + (size_t)r0 * D_ + c;
    u16* op = g + (size_t)r0 * D_ + c;
    #pragma unroll
    for (int rr = 0; rr < STRIP; ++rr) {
        u16x4 cb = *(const u16x4*)(base + (size_t)rr * D_);
        f32x4 vv = *(const f32x4*)(vp + (size_t)rr * D_);
        f32x4 cur;
        #pragma unroll
        for (int e = 0; e < 4; ++e) cur[e] = b2f(cb[e]);
        u16x4 outv;
        #pragma unroll
        for (int e = 0; e < 4; ++e) {
            float conv = w0 * m2[e] + w1 * m1[e] + w2 * cur[e];
            outv[e] = f2b(gelu_exact(conv * vv[e]));
        }
        *(u16x4*)(op + (size_t)rr * D_) = outv;
        m2 = m1; m1 = cur;
    }
}

// ---------------------------------------------------------------------------
extern "C" void kernel_launch(void* const* d_in, const int* in_sizes, int n_in,
                              void* d_out, int out_size, void* d_ws, size_t ws_size,
                              hipStream_t stream) {
    const float* x       = (const float*)d_in[0];
    const float* short_w = (const float*)d_in[1];
    const float* short_b = (const float*)d_in[2];
    const float* proj_w  = (const float*)d_in[3];
    const float* proj_b  = (const float*)d_in[4];
    const float* filt_w  = (const float*)d_in[5];
    const float* filt_b  = (const float*)d_in[6];
    const float* out_w   = (const float*)d_in[7];
    const float* out_b   = (const float*)d_in[8];
    float* out = (float*)d_out;

    // ws: wacc | t_g | xs bf16 32MB | g bf16 32MB | wT1 8MB [| wT2 8MB]
    char* ws = (char*)d_ws;
    const size_t xs_bytes = (size_t)MROWS * D_ * 2;   // 33,554,432
    const size_t wt_bytes = (size_t)KDIM * NDIM * 2;  // 8,388,608
    float* wacc = (float*)(ws);
    float* t_g  = (float*)(ws + 1024);                // 8192*6 fp32
    u16*   xs   = (u16*)(ws + 262144);
    u16*   g    = (u16*)(ws + 262144 + xs_bytes);
    u16*   wT1  = (u16*)(ws + 262144 + 2 * xs_bytes);
    const size_t need_dual = 262144 + 2 * xs_bytes + 2 * wt_bytes;
    const bool dual = (ws_size >= need_dual);
    u16* wT2 = dual ? (u16*)(ws + 262144 + 2 * xs_bytes + wt_bytes) : wT1;

    dim3 tb(32, 8, 1);

    if (dual) {
        dim3 tg(D_ / 32, D_ / 32, 2);
        transpose_k<<<tg, tb, 0, stream>>>(proj_w, wT1, out_w, wT2, D_);
    } else {
        dim3 tg(D_ / 32, D_ / 32, 1);
        transpose_k<<<tg, tb, 0, stream>>>(proj_w, wT1, proj_w, wT1, D_);
    }

    dim3 cg(2, MROWS / STRIP, 1);   // 1024 blocks
    shortconv_k<<<cg, 256, 0, stream>>>(x, short_w, short_b, xs, wacc, t_g);

    dim3 gg(NDIM / 256, MROWS / 256, 1);     // (8, 32) = 256 blocks
    gemm_f8<<<gg, 512, 0, stream>>>(xs, wT1, proj_b, filt_w, t_g);

    filt_finish_k<<<64, 256, 0, stream>>>(t_g, filt_b, wacc);

    if (!dual) {
        dim3 tg(D_ / 32, D_ / 32, 1);
        transpose_k<<<tg, tb, 0, stream>>>(out_w, wT2, out_w, wT2, D_);
    }

    gate_k<<<cg, 256, 0, stream>>>(xs, x, wacc, g);

    dim3 g2(NDIM / 128, MROWS / 256, 1);     // (16, 32) = 512 blocks, 2/CU
    gemm2_tlp<<<g2, 256, 0, stream>>>(g, wT2, out_b, out);
}